// Round 1
// 242.022 us; speedup vs baseline: 1.0388x; 1.0388x over previous
//
#include <hip/hip_runtime.h>
#include <math.h>

// ToneStack: 3 cascaded shelf biquads over x[64, 480000] fp32.
//
// R5: wave-contiguous stores via LDS transpose staging.
//   R4 structure kept intact (single fused kernel, block-local state
//   composition, 24-chunk history, Horner over A^64):
//     1. zero-state pass  -> d_t (6 floats) into LDS
//     2. block computes A^64 (6 LDS squarings), scalarized via readfirstlane
//     3. truncated Horner over 24 predecessor d's (1536-sample horizon)
//     4. re-run chunk from composed start state (register-resident)
//   NEW (R5): per-thread 256B-chunk stores had 256B lane stride -> every
//   128B L2 line collected 8 separate 16B writes across 8 instructions;
//   grid-wide store burst (157MB through 32MB L2) evicted lines partially
//   dirty -> 1.28x WRITE_SIZE amplification + RMW stalls (write-only
//   replay showed 1.17 TB/s). Now each wave's 16KB output is staged
//   through a 16KB LDS buffer (aliasing the dead dl region) in 4 rounds,
//   then stored cooperatively: each global_store_dwordx4 writes 1KB of
//   consecutive addresses -> every 128B line fully dirtied by a single
//   instruction. XOR swizzle (byte ^= (slot&7)<<4) keeps ds_write_b128 /
//   ds_read_b128 conflict-free. Output bitwise identical to R4.

constexpr int T_LEN  = 480000;
constexpr int B_ROWS = 64;
constexpr int CHUNK  = 64;
constexpr int LOG2C  = 6;                     // A^64 = 6 squarings
constexpr int KCH    = T_LEN / CHUNK;         // 7500 chunks per row
constexpr int NT     = 256;                   // threads per block
constexpr int HISTC  = 24;                    // history chunks (1536 samples)
constexpr int MTERM  = 24;                    // Horner terms (= horizon)
constexpr int OUTC   = NT - HISTC;            // 232 output chunks per block
constexpr int BLKROW = (KCH + OUTC - 1) / OUTC;  // 33 blocks per row
constexpr int NBLK   = B_ROWS * BLKROW;       // 2112 blocks
constexpr int NWAVE  = NT / 64;               // 4 staging rounds

struct Coeffs { float b0, b1, b2, a1, a2; };

__device__ __forceinline__ float rfl(float v) {
    return __int_as_float(__builtin_amdgcn_readfirstlane(__float_as_int(v)));
}

__device__ __forceinline__ Coeffs shelf(float fc, float gdb, float Q) {
    float A  = powf(10.0f, gdb * (1.0f / 40.0f));
    float w0 = 2.0f * 3.14159265358979323846f * fc / 48000.0f;
    float sw = sinf(w0), cw = cosf(w0);
    float alpha = sw / (2.0f * Q);
    float sqA = sqrtf(A);
    float b0 = A * ((A + 1.0f) - (A - 1.0f) * cw + 2.0f * sqA * alpha);
    float b1 = 2.0f * A * ((A - 1.0f) - (A + 1.0f) * cw);
    float b2 = A * ((A + 1.0f) - (A - 1.0f) * cw - 2.0f * sqA * alpha);
    float a0 = (A + 1.0f) + (A - 1.0f) * cw + 2.0f * sqA * alpha;
    float a1 = -2.0f * ((A - 1.0f) + (A + 1.0f) * cw);
    float a2 = (A + 1.0f) + (A - 1.0f) * cw - 2.0f * sqA * alpha;
    float rr = 1.0f / a0;
    Coeffs c;
    c.b0 = rfl(b0 * rr); c.b1 = rfl(b1 * rr); c.b2 = rfl(b2 * rr);
    c.a1 = rfl(a1 * rr); c.a2 = rfl(a2 * rr);
    return c;
}

// DF2T biquad step, op-for-op as reference:
//   y = b0*x + z1; z1' = b1*x - a1*y + z2; z2' = b2*x - a2*y
__device__ __forceinline__ float bq(float xn, const Coeffs& c, float& z1, float& z2) {
    float y = fmaf(c.b0, xn, z1);
    z1 = fmaf(-c.a1, y, fmaf(c.b1, xn, z2));
    z2 = fmaf(c.b2, xn, -(c.a2 * y));
    return y;
}

__device__ __forceinline__ float step6(float s[6], float x,
                                       const Coeffs& c1, const Coeffs& c2, const Coeffs& c3) {
    float y1 = bq(x,  c1, s[0], s[1]);
    float y2 = bq(y1, c2, s[2], s[3]);
    float y3 = bq(y2, c3, s[4], s[5]);
    return y3;
}

__global__ __launch_bounds__(256, 4) void k_fused(
    const float* __restrict__ x,
    const float* __restrict__ p_lg, const float* __restrict__ p_mg,
    const float* __restrict__ p_mf, const float* __restrict__ p_mq,
    const float* __restrict__ p_hg,
    float* __restrict__ out)
{
    // 16KB: first NT*7=1792 floats double as the per-thread d store (dl),
    // then (after a barrier) the whole thing is the store-staging buffer.
    __shared__ __align__(16) float smem[4096];
    __shared__ float M[36];        // A^64 workspace

    const int t = threadIdx.x;
    const int r = blockIdx.x / BLKROW;
    const int b = blockIdx.x - r * BLKROW;
    const int c = b * OUTC + t - HISTC;          // this thread's chunk index
    const bool active = (c >= 0) && (c < KCH);

    Coeffs c1 = shelf(120.0f,  *p_lg, 0.707f);
    Coeffs c2 = shelf(*p_mf,   *p_mg, *p_mq);
    Coeffs c3 = shelf(4000.0f, *p_hg, 0.707f);

    // ---- load chunk into registers ----
    float4 xv[16];
    {
        int cc = c < 0 ? 0 : c;
        const float4* lp = (const float4*)(x + (long long)r * T_LEN + (long long)cc * CHUNK);
        if (active) {
            #pragma unroll
            for (int q = 0; q < 16; ++q) xv[q] = lp[q];
        } else {
            #pragma unroll
            for (int q = 0; q < 16; ++q) xv[q] = make_float4(0.f, 0.f, 0.f, 0.f);
        }
    }

    // ---- pass 1: zero-state response of this chunk ----
    float s[6] = {0.f, 0.f, 0.f, 0.f, 0.f, 0.f};
    #pragma unroll
    for (int q = 0; q < 16; ++q) {
        step6(s, xv[q].x, c1, c2, c3);
        step6(s, xv[q].y, c1, c2, c3);
        step6(s, xv[q].z, c1, c2, c3);
        step6(s, xv[q].w, c1, c2, c3);
    }
    #pragma unroll
    for (int i = 0; i < 6; ++i) smem[t * 7 + i] = s[i];

    // ---- A^64 via 6 LDS squarings (threads 0..35 work) ----
    if (t < 6) {
        float e[6] = {0.f, 0.f, 0.f, 0.f, 0.f, 0.f};
        e[t] = 1.0f;
        step6(e, 0.0f, c1, c2, c3);              // column t of A
        #pragma unroll
        for (int i = 0; i < 6; ++i) M[i * 6 + t] = e[i];
    }
    __syncthreads();                              // covers dl + M writes
    for (int it = 0; it < LOG2C; ++it) {
        float acc = 0.f;
        if (t < 36) {
            int i = t / 6, j = t - 6 * (t / 6);
            #pragma unroll
            for (int q = 0; q < 6; ++q) acc = fmaf(M[i * 6 + q], M[q * 6 + j], acc);
        }
        __syncthreads();
        if (t < 36) M[t] = acc;
        __syncthreads();
    }
    float a[36];
    #pragma unroll
    for (int i = 0; i < 36; ++i) a[i] = rfl(M[i]);   // wave-uniform -> SGPR

    // ---- truncated Horner scan over predecessors (oldest -> newest) ----
    float t6[6] = {0.f, 0.f, 0.f, 0.f, 0.f, 0.f};
    int m0 = t - MTERM; if (m0 < 0) m0 = 0;
    for (int m = m0; m < t; ++m) {
        float dm[6];
        #pragma unroll
        for (int i = 0; i < 6; ++i) dm[i] = smem[m * 7 + i];
        float nt6[6];
        #pragma unroll
        for (int i = 0; i < 6; ++i) {
            float acc = dm[i];
            #pragma unroll
            for (int j = 0; j < 6; ++j) acc = fmaf(a[i * 6 + j], t6[j], acc);
            nt6[i] = acc;
        }
        #pragma unroll
        for (int i = 0; i < 6; ++i) t6[i] = nt6[i];
    }

    // ---- pass 2: re-run from composed start state, in place ----
    #pragma unroll
    for (int q = 0; q < 16; ++q) {
        float4 v = xv[q];
        v.x = step6(t6, v.x, c1, c2, c3);
        v.y = step6(t6, v.y, c1, c2, c3);
        v.z = step6(t6, v.z, c1, c2, c3);
        v.w = step6(t6, v.w, c1, c2, c3);
        xv[q] = v;
    }

    // ---- wave-contiguous stores via LDS transpose staging ----
    // Round rr: wave rr writes its 64 chunks (16KB) into smem (swizzled),
    // then ALL 256 threads store it as 4x float4 each -> every
    // global_store_dwordx4 covers 1KB of consecutive addresses (128B L2
    // lines fully dirtied by a single instruction -> no partial-dirty
    // evictions, no write amplification).
    __syncthreads();                              // all dl (smem) reads done
    float4* sv = (float4*)smem;
    const int slot = t & 63;                      // lane within wave
    const int wv   = t >> 6;                      // wave id
    float4* op = (float4*)(out + (long long)r * T_LEN);
    for (int rr = 0; rr < NWAVE; ++rr) {
        if (wv == rr) {
            #pragma unroll
            for (int q = 0; q < 16; ++q) {
                int byte = (slot * 256 + q * 16) ^ ((slot & 7) << 4);
                sv[byte >> 4] = xv[q];
            }
        }
        __syncthreads();                          // stage visible to block
        const int chunkBase = b * OUTC + 64 * rr - HISTC;  // chunk of slot 0
        #pragma unroll
        for (int j = 0; j < 4; ++j) {
            int f  = 256 * j + t;                 // float4 index in 16KB region
            int aa = f >> 4;                      // source slot (0..63)
            int qq = f & 15;                      // float4 within chunk
            int tr = 64 * rr + aa;                // owning thread index
            int cc = chunkBase + aa;              // destination chunk
            if (tr >= HISTC && cc < KCH) {
                int byte = (aa * 256 + qq * 16) ^ ((aa & 7) << 4);
                op[(long long)cc * 16 + qq] = sv[byte >> 4];
            }
        }
        __syncthreads();                          // stage reusable next round
    }
}

extern "C" void kernel_launch(void* const* d_in, const int* in_sizes, int n_in,
                              void* d_out, int out_size, void* d_ws, size_t ws_size,
                              hipStream_t stream) {
    const float* x  = (const float*)d_in[0];
    const float* lg = (const float*)d_in[1];
    const float* mg = (const float*)d_in[2];
    const float* mf = (const float*)d_in[3];
    const float* mq = (const float*)d_in[4];
    const float* hg = (const float*)d_in[5];
    float* out = (float*)d_out;

    hipLaunchKernelGGL(k_fused, dim3(NBLK), dim3(NT), 0, stream,
                       x, lg, mg, mf, mq, hg, out);
}